// Round 10
// baseline (471.739 us; speedup 1.0000x reference)
//
#include <hip/hip_runtime.h>

// ConvSNN forward, T=16, B=128. One kernel per LAYER, t-loop inside, LIF state
// in REGISTERS. conv2/conv3/fc1 via MFMA bf16 with TRIPLE-split weights
// (hi+mid+lo ~= fp32 to ~2^-27 rel); activations are pooled spikes in
// {0,.25,.5,.75,1}, exact in bf16.
// This round: A-frag hoist across splits, padded B-frag strides (bank-conflict
// free), 2 blocks/CU everywhere, wave-local pooling, division-free staging.

typedef __attribute__((ext_vector_type(8))) short bf16x8;
typedef __attribute__((ext_vector_type(4))) float f32x4;

__device__ __forceinline__ unsigned short f2bf(float f) {
  unsigned int u = __float_as_uint(f);
  return (unsigned short)((u + 0x7fffu + ((u >> 16) & 1u)) >> 16);
}
__device__ __forceinline__ float bf2f(unsigned short h) {
  return __uint_as_float(((unsigned int)h) << 16);
}
__device__ __forceinline__ unsigned short split3(float wv, int sp) {
  unsigned short hi = f2bf(wv);
  float r1 = wv - bf2f(hi);
  unsigned short mid = f2bf(r1);
  if (sp == 0) return hi;
  if (sp == 1) return mid;
  return f2bf(r1 - bf2f(mid));
}
__device__ __forceinline__ float lif1(float inp, float vth, float& v, float& i) {
  float vd = fmaf(0.1f, i - v, v);
  float z = (vd > vth) ? 1.0f : 0.0f;
  v = (vd > vth) ? 0.0f : vd;
  i = fmaf(0.8f, i, inp);
  return z;
}
__device__ __forceinline__ f32x4 mfma16(bf16x8 a, bf16x8 b, f32x4 c) {
  return __builtin_amdgcn_mfma_f32_16x16x32_bf16(a, b, c, 0, 0, 0);
}

// ---------- one-time weight split+pack into B-fragment order ----------
// conv2 layout: [ocg 2][sp 3][dydx 9][g 4][ocl 32][j 8]  (ic = 8g+j); 55296
__global__ __launch_bounds__(256) void k_pack2(const float* __restrict__ wc2,
                                               unsigned short* __restrict__ wpk) {
  int idx = blockIdx.x * 256 + threadIdx.x;
  if (idx >= 55296) return;
  int j = idx & 7, ocl = (idx >> 3) & 31, g = (idx >> 8) & 3;
  int r = idx >> 10;
  int dydx = r % 9; int q = r / 9;
  int sp = q % 3, ocg = q / 3;
  int oc = ocg * 32 + ocl, ic = g * 8 + j;
  wpk[idx] = split3(wc2[(oc * 32 + ic) * 9 + dydx], sp);
}
// conv3 layout: [ocg 8][ics 2][sp 3][dydx 9][g 4][ocl 16][j 8]; 442368
__global__ __launch_bounds__(256) void k_pack3(const float* __restrict__ wc3,
                                               unsigned short* __restrict__ wpk) {
  int idx = blockIdx.x * 256 + threadIdx.x;
  if (idx >= 442368) return;
  int j = idx & 7, ocl = (idx >> 3) & 15, g = (idx >> 7) & 3;
  int r = idx >> 9;
  int dydx = r % 9; int q = r / 9;
  int sp = q % 3; int q2 = q / 3;
  int ics = q2 & 1, ocg = q2 >> 1;
  int oc = ocg * 16 + ocl, ic = ics * 32 + g * 8 + j;
  wpk[idx] = split3(wc3[(oc * 64 + ic) * 9 + dydx], sp);
}

// ---------- conv1 (3->32) fp32, t-loop, state in regs -> z1bf[t] (B,16,16,32) ----------
// grid 1024 = b(128) x h(2) x g(4: 8 oc); 256 thr; staging offsets precomputed.
__global__ __launch_bounds__(256) void k_conv1(const float* __restrict__ x,
    const float* __restrict__ wc, unsigned short* __restrict__ z1bf)
{
  const int bid = blockIdx.x;
  const int g = bid & 3, h = (bid >> 2) & 1, b = bid >> 3;
  const int tid = threadIdx.x;
  __shared__ float xs[3][18][34];
  __shared__ __align__(16) float wl[8][28];
  for (int i = tid; i < 216; i += 256) wl[i / 27][i % 27] = wc[g * 216 + i];
  // precompute staging source offsets (t-invariant)
  int ssrc[8];
#pragma unroll
  for (int k2 = 0; k2 < 8; ++k2) {
    int i = tid + k2 * 256;
    int v = -1;
    if (i < 1836) {
      int c = i / 612, rr = i % 612;
      int row = rr / 34, col = rr % 34;
      int gy = h * 16 + row - 1, gx = col - 1;
      if (gy >= 0 && gy < 32 && gx >= 0 && gx < 32) v = c * 1024 + gy * 32 + gx;
    }
    ssrc[k2] = v;
  }
  const int site = tid >> 1, sub = tid & 1;
  const int ph = site >> 4, pw = site & 15;
  const int py = h * 8 + ph;
  float vst[4][4], ist[4][4];
#pragma unroll
  for (int jj = 0; jj < 4; ++jj)
#pragma unroll
    for (int r = 0; r < 4; ++r) { vst[jj][r] = 0.f; ist[jj][r] = 0.f; }

  for (int t = 0; t < 16; ++t) {
    __syncthreads();
    const float* xt = x + (size_t)t * 393216 + b * 3072;
    float* xsf = &xs[0][0][0];
#pragma unroll
    for (int k2 = 0; k2 < 8; ++k2) {
      int i = tid + k2 * 256;
      if (i < 1836) xsf[i] = (ssrc[k2] >= 0) ? xt[ssrc[k2]] : 0.f;
    }
    __syncthreads();
    float p[3][4][4];
#pragma unroll
    for (int c = 0; c < 3; ++c)
#pragma unroll
      for (int r = 0; r < 4; ++r)
#pragma unroll
        for (int cc = 0; cc < 4; ++cc)
          p[c][r][cc] = xs[c][2 * ph + r][2 * pw + cc];
    unsigned short zout[4];
#pragma unroll
    for (int jj = 0; jj < 4; ++jj) {
      float wreg[28];
      const float4* wrow = (const float4*)&wl[sub * 4 + jj][0];
#pragma unroll
      for (int u = 0; u < 7; ++u) *(float4*)&wreg[u * 4] = wrow[u];
      float s00 = 0, s01 = 0, s10 = 0, s11 = 0;
#pragma unroll
      for (int c = 0; c < 3; ++c)
#pragma unroll
        for (int kh = 0; kh < 3; ++kh)
#pragma unroll
          for (int kw = 0; kw < 3; ++kw) {
            float wvv = wreg[(c * 3 + kh) * 3 + kw];
            s00 = fmaf(p[c][kh][kw],     wvv, s00);
            s01 = fmaf(p[c][kh][kw+1],   wvv, s01);
            s10 = fmaf(p[c][kh+1][kw],   wvv, s10);
            s11 = fmaf(p[c][kh+1][kw+1], wvv, s11);
          }
      float z0 = lif1(s00, 0.25f, vst[jj][0], ist[jj][0]);
      float z1 = lif1(s01, 0.25f, vst[jj][1], ist[jj][1]);
      float z2 = lif1(s10, 0.25f, vst[jj][2], ist[jj][2]);
      float z3 = lif1(s11, 0.25f, vst[jj][3], ist[jj][3]);
      zout[jj] = f2bf(0.25f * (z0 + z1 + z2 + z3));
    }
    *(uint2*)&z1bf[(size_t)t * 1048576 + ((b * 16 + py) * 16 + pw) * 32 + g * 8 + sub * 4]
        = *(uint2*)zout;
  }
}

// ---------- conv2 (32->64) MFMA, 1 img/block, wave-local pool -> z2bf[t] ----------
// grid 512 = ocg(2) x h(2) x b(128); 512 thr = 8 waves (xh 2 x rp 4).
// LDS: wl 57024 (pad 264) + img 14400 + zpl 8704 = 80128 B -> 2 blocks/CU.
__global__ __launch_bounds__(512) void k_conv2(const unsigned short* __restrict__ z1bf,
    const unsigned short* __restrict__ wpk, unsigned short* __restrict__ z2bf)
{
  const int bid = blockIdx.x;
  const int ocg = bid & 1, h = (bid >> 1) & 1, b = bid >> 2;
  const int tid = threadIdx.x;
  __shared__ __align__(16) unsigned short wl[28512];     // 108 frags x 264 sh
  __shared__ __align__(16) unsigned short img[10][18][40];
  __shared__ __align__(16) unsigned short zpl[8][16][34];
  {
    const uint4* wsrc = (const uint4*)(wpk + ocg * 27648);
    uint4* wd = (uint4*)wl;
    for (int i = tid; i < 3456; i += 512) {
      int f = i >> 5, u = i & 31;
      wd[f * 33 + u] = wsrc[i];
    }
  }
  // precompute img staging (t-invariant): 900 uint4 slots
  int csrc[2];
#pragma unroll
  for (int k2 = 0; k2 < 2; ++k2) {
    int e = tid + k2 * 512;
    int v = -1;
    if (e < 900) {
      int s = e / 5, u = e % 5;
      int row = s / 18, col = s % 18;
      int gy = h * 8 + row - 1, gx = col - 1;
      if (u < 4 && gy >= 0 && gy < 16 && gx >= 0 && gx < 16)
        v = ((b * 16 + gy) * 16 + gx) * 32 + u * 8;
    }
    csrc[k2] = v;
  }
  const int w = tid >> 6, l = tid & 63;
  const int xh = w & 1, rp = w >> 1;
  const int lg = l >> 4, ll = l & 15;
  const int ry = ll >> 3, xi = ll & 7;
  unsigned short* zw = &zpl[w][0][0];
  const int oc_r = l & 31, jj = l >> 5;
  float vst[2][4], ist[2][4];
#pragma unroll
  for (int tl = 0; tl < 2; ++tl)
#pragma unroll
    for (int r = 0; r < 4; ++r) { vst[tl][r] = 0.f; ist[tl][r] = 0.f; }

  for (int t = 0; t < 16; ++t) {
    __syncthreads();                       // prior-t img readers done (covers wl at t=0)
    {
      const unsigned short* zt = z1bf + (size_t)t * 1048576;
      uint4* imgu4 = (uint4*)&img[0][0][0];
#pragma unroll
      for (int k2 = 0; k2 < 2; ++k2) {
        int e = tid + k2 * 512;
        if (e < 900) {
          uint4 val = {0, 0, 0, 0};
          if (csrc[k2] >= 0) val = *(const uint4*)(zt + csrc[k2]);
          imgu4[e] = val;
        }
      }
    }
    __syncthreads();
    f32x4 acc[2] = {};
    for (int s9 = 0; s9 < 9; ++s9) {
      const int dy = s9 / 3, dx = s9 % 3;
      bf16x8 a = *(const bf16x8*)&img[2 * rp + ry + dy][xh * 8 + xi + dx][8 * lg];
#pragma unroll
      for (int sp = 0; sp < 3; ++sp) {
#pragma unroll
        for (int tl = 0; tl < 2; ++tl) {
          bf16x8 bw = *(const bf16x8*)&wl[((sp * 9 + s9) * 4 + lg) * 264 + (tl * 16 + ll) * 8];
          acc[tl] = mfma16(a, bw, acc[tl]);
        }
      }
    }
    // LIF + wave-local pool (no barrier: zpl region is per-wave)
#pragma unroll
    for (int tl = 0; tl < 2; ++tl)
#pragma unroll
      for (int r = 0; r < 4; ++r) {
        int m = 4 * lg + r;
        float z = lif1(acc[tl][r], 0.2f, vst[tl][r], ist[tl][r]);
        zw[m * 34 + tl * 16 + ll] = f2bf(z);
      }
#pragma unroll
    for (int jp = 0; jp < 2; ++jp) {
      int j = jj + 2 * jp;
      float zsum = bf2f(zw[(2*j)*34 + oc_r])     + bf2f(zw[(2*j+1)*34 + oc_r]) +
                   bf2f(zw[(8+2*j)*34 + oc_r])   + bf2f(zw[(9+2*j)*34 + oc_r]);
      z2bf[(size_t)t * 524288 + ((b * 8 + h * 4 + rp) * 8 + xh * 4 + j) * 64 +
           ocg * 32 + oc_r] = f2bf(0.25f * zsum);
    }
  }
}

// ---------- conv3 (64->128) MFMA full-K, 1 img/block, wave-local pool -> z3t[t] ----------
// grid 1024 = ocg(8: 16 oc) x b(128); 256 thr = 4 waves (row-pairs).
// LDS: wl 58752 (pad 136) + img 17280 + zpl 2304 = 78336 B -> 2 blocks/CU.
__global__ __launch_bounds__(256) void k_conv3(const unsigned short* __restrict__ z2bf,
    const unsigned short* __restrict__ wpk, unsigned short* __restrict__ z3t)
{
  const int bid = blockIdx.x;
  const int ocg = bid & 7, b = bid >> 3;
  const int tid = threadIdx.x;
  __shared__ __align__(16) unsigned short wl[29376];     // 216 frags x 136 sh
  __shared__ __align__(16) unsigned short img[10][12][72];
  __shared__ __align__(16) unsigned short zpl[4][16][18];
  {
    const uint4* wsrc = (const uint4*)(wpk + ocg * 27648);
    uint4* wd = (uint4*)wl;
    for (int i = tid; i < 3456; i += 256) {
      int f = i >> 4, u = i & 15;
      wd[f * 17 + u] = wsrc[i];
    }
  }
  int csrc[5];
#pragma unroll
  for (int k2 = 0; k2 < 5; ++k2) {
    int e = tid + k2 * 256;
    int v = -1;
    if (e < 1080) {
      int s = e / 9, u = e % 9;
      int row = s / 12, col = s % 12;
      int gy = row - 1, gx = col - 1;
      if (u < 8 && gy >= 0 && gy < 8 && gx >= 0 && gx < 8)
        v = ((b * 8 + gy) * 8 + gx) * 64 + u * 8;
    }
    csrc[k2] = v;
  }
  const int w = tid >> 6, l = tid & 63;
  const int lg = l >> 4, ll = l & 15;
  const int ry = ll >> 3, xi = ll & 7;
  float vst[4], ist[4];
#pragma unroll
  for (int r = 0; r < 4; ++r) { vst[r] = 0.f; ist[r] = 0.f; }

  for (int t = 0; t < 16; ++t) {
    __syncthreads();
    {
      const unsigned short* zt = z2bf + (size_t)t * 524288;
      uint4* imgu4 = (uint4*)&img[0][0][0];
#pragma unroll
      for (int k2 = 0; k2 < 5; ++k2) {
        int e = tid + k2 * 256;
        if (e < 1080) {
          uint4 val = {0, 0, 0, 0};
          if (csrc[k2] >= 0) val = *(const uint4*)(zt + csrc[k2]);
          imgu4[e] = val;
        }
      }
    }
    __syncthreads();
    f32x4 acc = {};
    for (int ics = 0; ics < 2; ++ics) {
      for (int s9 = 0; s9 < 9; ++s9) {
        const int dy = s9 / 3, dx = s9 % 3;
        bf16x8 a = *(const bf16x8*)&img[2 * w + ry + dy][xi + dx][ics * 32 + 8 * lg];
#pragma unroll
        for (int sp = 0; sp < 3; ++sp) {
          bf16x8 bw = *(const bf16x8*)&wl[(((ics * 3 + sp) * 9 + s9) * 4 + lg) * 136 + ll * 8];
          acc = mfma16(a, bw, acc);
        }
      }
    }
    // LIF + wave-local pool (zpl region per-wave; no barrier)
#pragma unroll
    for (int r = 0; r < 4; ++r) {
      int px = 4 * lg + r;
      float z = lif1(acc[r], 0.1f, vst[r], ist[r]);
      zpl[w][px][ll] = f2bf(z);
    }
    float zsum = bf2f(zpl[w][2*lg][ll])   + bf2f(zpl[w][2*lg+1][ll]) +
                 bf2f(zpl[w][8+2*lg][ll]) + bf2f(zpl[w][9+2*lg][ll]);
    z3t[(size_t)t * 262144 + b * 2048 + (ocg * 16 + ll) * 16 + w * 4 + lg]
        = f2bf(0.25f * zsum);
  }
}

// ---------- fc1 (2048->1024) MFMA, K-split 8 -> P1[t][kb][b][n] ----------
// grid 1024 = kb8 x nb64(16 n) x bb2; 256 thr = 4 waves (bt).
// LDS: slab 32768 + wl3 26112 (pad 136) = 58880 B -> 2 blocks/CU.
__global__ __launch_bounds__(256) void k_fc1(const unsigned short* __restrict__ z3t,
    const float* __restrict__ wf1, float* __restrict__ P1)
{
  const int bid = blockIdx.x;
  const int kb = bid & 7, nb = (bid >> 3) & 63, bb = bid >> 9;
  const int tid = threadIdx.x;
  __shared__ __align__(16) unsigned short slab[16384];   // [64 b][32 grp^swz][8]
  __shared__ __align__(16) unsigned short wl3[13056];    // [sp3][32 frags x 136]
  for (int i = tid; i < 12288; i += 256) {
    int sp = i >> 12, rem = i & 4095;
    int f = rem >> 7, e = rem & 127;
    int n = e >> 3, j = e & 7;
    int ks = f >> 2, g = f & 3;
    float wv = wf1[(size_t)(nb * 16 + n) * 2048 + kb * 256 + ks * 32 + g * 8 + j];
    wl3[sp * 4352 + f * 136 + e] = split3(wv, sp);
  }
  const int w = tid >> 6, l = tid & 63;
  const int lg = l >> 4, ll = l & 15;
  const int arow = w * 16 + ll;
  const int bo = bb * 64 + w * 16;

  for (int t = 0; t < 16; ++t) {
    __syncthreads();                      // prior-t slab readers done (covers wl3 at t=0)
    for (int gidx = tid; gidx < 2048; gidx += 256) {
      int row = gidx >> 5, gc = gidx & 31;
      const uint4* s = (const uint4*)(z3t + (size_t)t * 262144 +
                                      ((bb * 64 + row) * 2048 + kb * 256 + gc * 8));
      ((uint4*)slab)[row * 32 + (gc ^ (row & 7))] = *s;
    }
    __syncthreads();
    f32x4 acc = {};
#pragma unroll
    for (int ks = 0; ks < 8; ++ks) {
      bf16x8 a = *(const bf16x8*)&slab[(arow * 32 + ((ks * 4 + lg) ^ (arow & 7))) * 8];
#pragma unroll
      for (int sp = 0; sp < 3; ++sp) {
        bf16x8 bw = *(const bf16x8*)&wl3[sp * 4352 + (ks * 4 + lg) * 136 + ll * 8];
        acc = mfma16(a, bw, acc);
      }
    }
    float* Pt = P1 + (size_t)t * 1048576 + (size_t)kb * 131072;
#pragma unroll
    for (int r = 0; r < 4; ++r)
      Pt[(bo + 4 * lg + r) * 1024 + nb * 16 + ll] = acc[r];
  }
}

// ---------- fc1 reduce + LIF(0.1), t-loop, state in regs -> z4bf[t][b][n] ----------
__global__ __launch_bounds__(256) void k_fc1b(const float* __restrict__ P1,
    unsigned short* __restrict__ z4bf)
{
  const int site = blockIdx.x * 256 + threadIdx.x;   // 131072 = b*1024+n
  float v = 0.f, ii = 0.f;
  for (int t = 0; t < 16; ++t) {
    const float* p = P1 + (size_t)t * 1048576 + site;
    float a = 0.f;
#pragma unroll
    for (int kb = 0; kb < 8; ++kb) a += p[(size_t)kb * 131072];
    float z = lif1(a, 0.1f, v, ii);
    z4bf[(size_t)t * 131072 + site] = f2bf(z);
  }
}

// ---------- out layer (1024->10) + LI + running max, t-loop, state in regs ----------
__global__ __launch_bounds__(256) void k_out(const unsigned short* __restrict__ z4bf,
    const float* __restrict__ wo, float* __restrict__ out)
{
  const int w = threadIdx.x >> 6, l = threadIdx.x & 63;
  const int b = blockIdx.x * 4 + w;
  float vo[10], io[10], om[10];
#pragma unroll
  for (int o = 0; o < 10; ++o) { vo[o] = 0.f; io[o] = 0.f; om[o] = 0.f; }
  for (int t = 0; t < 16; ++t) {
    float dot[10];
#pragma unroll
    for (int o = 0; o < 10; ++o) dot[o] = 0.f;
    for (int c = 0; c < 16; ++c) {
      const int n = c * 64 + l;
      float z = bf2f(z4bf[(size_t)t * 131072 + b * 1024 + n]);
#pragma unroll
      for (int o = 0; o < 10; ++o) dot[o] = fmaf(z, wo[o * 1024 + n], dot[o]);
    }
#pragma unroll
    for (int o = 0; o < 10; ++o)
#pragma unroll
      for (int d = 32; d > 0; d >>= 1) dot[o] += __shfl_down(dot[o], d);
    if (l == 0) {
#pragma unroll
      for (int o = 0; o < 10; ++o) {
        float vn = fmaf(0.1f, io[o] - vo[o], vo[o]);
        io[o] = fmaf(0.8f, io[o], dot[o]);
        vo[o] = vn;
        om[o] = (t == 0) ? vn : fmaxf(om[o], vn);
      }
    }
  }
  if (l == 0) {
#pragma unroll
    for (int o = 0; o < 10; ++o) out[b * 10 + o] = om[o];
  }
}

extern "C" void kernel_launch(void* const* d_in, const int* in_sizes, int n_in,
                              void* d_out, int out_size, void* d_ws, size_t ws_size,
                              hipStream_t stream)
{
  const float* x   = (const float*)d_in[0];   // (16,128,3,32,32)
  const float* wc1 = (const float*)d_in[1];   // (32,3,3,3)
  const float* wc2 = (const float*)d_in[2];   // (64,32,3,3)
  const float* wc3 = (const float*)d_in[3];   // (128,64,3,3)
  const float* wf1 = (const float*)d_in[4];   // (1024,2048)
  const float* wo  = (const float*)d_in[5];   // (10,1024)
  float* out = (float*)d_out;                 // (128,10)
  char* ws = (char*)d_ws;

  unsigned short* z1bf = (unsigned short*)(ws + 0);          // [16][128,16,16,32]
  unsigned short* z2bf = (unsigned short*)(ws + 33554432);   // [16][128,8,8,64]
  unsigned short* z3t  = (unsigned short*)(ws + 50331648);   // [16][128,2048]
  unsigned short* z4bf = (unsigned short*)(ws + 58720256);   // [16][128,1024]
  float* P1            = (float*)(ws + 62914560);            // [16][8][131072]
  unsigned short* wc2pk = (unsigned short*)(ws + 130023424);
  unsigned short* wc3pk = (unsigned short*)(ws + 130134016);

  k_pack2<<<216, 256, 0, stream>>>(wc2, wc2pk);
  k_pack3<<<1728, 256, 0, stream>>>(wc3, wc3pk);

  k_conv1<<<1024, 256, 0, stream>>>(x, wc1, z1bf);
  k_conv2<<<512, 512, 0, stream>>>(z1bf, wc2pk, z2bf);
  k_conv3<<<1024, 256, 0, stream>>>(z2bf, wc3pk, z3t);
  k_fc1 <<<1024, 256, 0, stream>>>(z3t, wf1, P1);
  k_fc1b<<<512, 256, 0, stream>>>(P1, z4bf);
  k_out <<<32, 256, 0, stream>>>(z4bf, wo, out);
}

// Round 11
// 398.842 us; speedup vs baseline: 1.1828x; 1.1828x over previous
//
#include <hip/hip_runtime.h>

// ConvSNN forward, T=16, B=128. One kernel per LAYER, t-loop inside, LIF state
// in REGISTERS. conv2/conv3/fc1 via MFMA bf16 with TRIPLE-split weights
// (hi+mid+lo ~= fp32 to ~2^-27 rel); activations are pooled spikes, exact bf16.
// THIS ROUND: B-fragments (t-invariant weights) live in REGISTERS, loaded once
// and reused across all 16 timesteps -> eliminates the dominant LDS-read traffic.

typedef __attribute__((ext_vector_type(8))) short bf16x8;
typedef __attribute__((ext_vector_type(4))) float f32x4;

__device__ __forceinline__ unsigned short f2bf(float f) {
  unsigned int u = __float_as_uint(f);
  return (unsigned short)((u + 0x7fffu + ((u >> 16) & 1u)) >> 16);
}
__device__ __forceinline__ float bf2f(unsigned short h) {
  return __uint_as_float(((unsigned int)h) << 16);
}
__device__ __forceinline__ unsigned short split3(float wv, int sp) {
  unsigned short hi = f2bf(wv);
  float r1 = wv - bf2f(hi);
  unsigned short mid = f2bf(r1);
  if (sp == 0) return hi;
  if (sp == 1) return mid;
  return f2bf(r1 - bf2f(mid));
}
__device__ __forceinline__ float lif1(float inp, float vth, float& v, float& i) {
  float vd = fmaf(0.1f, i - v, v);
  float z = (vd > vth) ? 1.0f : 0.0f;
  v = (vd > vth) ? 0.0f : vd;
  i = fmaf(0.8f, i, inp);
  return z;
}
__device__ __forceinline__ f32x4 mfma16(bf16x8 a, bf16x8 b, f32x4 c) {
  return __builtin_amdgcn_mfma_f32_16x16x32_bf16(a, b, c, 0, 0, 0);
}

// ---------- one-time weight split+pack into B-fragment order ----------
// conv2 layout: [ocg 4][sp 3][dydx 9][g 4][ocl 16][j 8]  (ic = 8g+j); 55296
__global__ __launch_bounds__(256) void k_pack2(const float* __restrict__ wc2,
                                               unsigned short* __restrict__ wpk) {
  int idx = blockIdx.x * 256 + threadIdx.x;
  if (idx >= 55296) return;
  int j = idx & 7, ocl = (idx >> 3) & 15, g = (idx >> 7) & 3;
  int r = idx >> 9;                         // 0..107
  int dydx = r % 9; int q = r / 9;          // 0..11
  int sp = q % 3, ocg = q / 3;
  int oc = ocg * 16 + ocl, ic = g * 8 + j;
  wpk[idx] = split3(wc2[(oc * 32 + ic) * 9 + dydx], sp);
}
// conv3 layout: [ocg 8][ics 2][sp 3][dydx 9][g 4][ocl 16][j 8]; 442368
__global__ __launch_bounds__(256) void k_pack3(const float* __restrict__ wc3,
                                               unsigned short* __restrict__ wpk) {
  int idx = blockIdx.x * 256 + threadIdx.x;
  if (idx >= 442368) return;
  int j = idx & 7, ocl = (idx >> 3) & 15, g = (idx >> 7) & 3;
  int r = idx >> 9;
  int dydx = r % 9; int q = r / 9;
  int sp = q % 3; int q2 = q / 3;
  int ics = q2 & 1, ocg = q2 >> 1;
  int oc = ocg * 16 + ocl, ic = ics * 32 + g * 8 + j;
  wpk[idx] = split3(wc3[(oc * 64 + ic) * 9 + dydx], sp);
}

// ---------- conv1 (3->32) fp32, t-loop, state in regs -> z1bf[t] (B,16,16,32) ----------
// grid 1024 = b(128) x h(2) x g(4: 8 oc); 256 thr. (unchanged from round 10)
__global__ __launch_bounds__(256) void k_conv1(const float* __restrict__ x,
    const float* __restrict__ wc, unsigned short* __restrict__ z1bf)
{
  const int bid = blockIdx.x;
  const int g = bid & 3, h = (bid >> 2) & 1, b = bid >> 3;
  const int tid = threadIdx.x;
  __shared__ float xs[3][18][34];
  __shared__ __align__(16) float wl[8][28];
  for (int i = tid; i < 216; i += 256) wl[i / 27][i % 27] = wc[g * 216 + i];
  int ssrc[8];
#pragma unroll
  for (int k2 = 0; k2 < 8; ++k2) {
    int i = tid + k2 * 256;
    int v = -1;
    if (i < 1836) {
      int c = i / 612, rr = i % 612;
      int row = rr / 34, col = rr % 34;
      int gy = h * 16 + row - 1, gx = col - 1;
      if (gy >= 0 && gy < 32 && gx >= 0 && gx < 32) v = c * 1024 + gy * 32 + gx;
    }
    ssrc[k2] = v;
  }
  const int site = tid >> 1, sub = tid & 1;
  const int ph = site >> 4, pw = site & 15;
  const int py = h * 8 + ph;
  float vst[4][4], ist[4][4];
#pragma unroll
  for (int jj = 0; jj < 4; ++jj)
#pragma unroll
    for (int r = 0; r < 4; ++r) { vst[jj][r] = 0.f; ist[jj][r] = 0.f; }

  for (int t = 0; t < 16; ++t) {
    __syncthreads();
    const float* xt = x + (size_t)t * 393216 + b * 3072;
    float* xsf = &xs[0][0][0];
#pragma unroll
    for (int k2 = 0; k2 < 8; ++k2) {
      int i = tid + k2 * 256;
      if (i < 1836) xsf[i] = (ssrc[k2] >= 0) ? xt[ssrc[k2]] : 0.f;
    }
    __syncthreads();
    float p[3][4][4];
#pragma unroll
    for (int c = 0; c < 3; ++c)
#pragma unroll
      for (int r = 0; r < 4; ++r)
#pragma unroll
        for (int cc = 0; cc < 4; ++cc)
          p[c][r][cc] = xs[c][2 * ph + r][2 * pw + cc];
    unsigned short zout[4];
#pragma unroll
    for (int jj = 0; jj < 4; ++jj) {
      float wreg[28];
      const float4* wrow = (const float4*)&wl[sub * 4 + jj][0];
#pragma unroll
      for (int u = 0; u < 7; ++u) *(float4*)&wreg[u * 4] = wrow[u];
      float s00 = 0, s01 = 0, s10 = 0, s11 = 0;
#pragma unroll
      for (int c = 0; c < 3; ++c)
#pragma unroll
        for (int kh = 0; kh < 3; ++kh)
#pragma unroll
          for (int kw = 0; kw < 3; ++kw) {
            float wvv = wreg[(c * 3 + kh) * 3 + kw];
            s00 = fmaf(p[c][kh][kw],     wvv, s00);
            s01 = fmaf(p[c][kh][kw+1],   wvv, s01);
            s10 = fmaf(p[c][kh+1][kw],   wvv, s10);
            s11 = fmaf(p[c][kh+1][kw+1], wvv, s11);
          }
      float z0 = lif1(s00, 0.25f, vst[jj][0], ist[jj][0]);
      float z1 = lif1(s01, 0.25f, vst[jj][1], ist[jj][1]);
      float z2 = lif1(s10, 0.25f, vst[jj][2], ist[jj][2]);
      float z3 = lif1(s11, 0.25f, vst[jj][3], ist[jj][3]);
      zout[jj] = f2bf(0.25f * (z0 + z1 + z2 + z3));
    }
    *(uint2*)&z1bf[(size_t)t * 1048576 + ((b * 16 + py) * 16 + pw) * 32 + g * 8 + sub * 4]
        = *(uint2*)zout;
  }
}

// ---------- conv2 (32->64) MFMA, B in REGS (27 frags), wave = 4 rows ----------
// grid 512 = ocg(4: 16 oc) x b(128); 256 thr = 4 waves.
__global__ __launch_bounds__(256, 2) void k_conv2(const unsigned short* __restrict__ z1bf,
    const unsigned short* __restrict__ wpk, unsigned short* __restrict__ z2bf)
{
  const int ocg = blockIdx.x & 3, b = blockIdx.x >> 2;
  const int tid = threadIdx.x;
  __shared__ __align__(16) unsigned short img[18][18][40];
  __shared__ __align__(16) unsigned short zpl[4][4][16][18];
  const int w = tid >> 6, l = tid & 63;
  const int lg = l >> 4, ll = l & 15;
  const int ry = ll >> 3, xi = ll & 7;
  // B fragments in registers, loaded once (t-invariant)
  bf16x8 bw[3][9];
  {
    const unsigned short* wp = wpk + ocg * 13824;
#pragma unroll
    for (int sp = 0; sp < 3; ++sp)
#pragma unroll
      for (int s9 = 0; s9 < 9; ++s9)
        bw[sp][s9] = *(const bf16x8*)(wp + ((sp * 9 + s9) * 4 + lg) * 128 + ll * 8);
  }
  int csrc[7];
#pragma unroll
  for (int k2 = 0; k2 < 7; ++k2) {
    int e = tid + k2 * 256;
    int v = -1;
    if (e < 1620) {
      int s = e / 5, u = e % 5;
      int row = s / 18, col = s % 18;
      int gy = row - 1, gx = col - 1;
      if (u < 4 && gy >= 0 && gy < 16 && gx >= 0 && gx < 16)
        v = ((b * 16 + gy) * 16 + gx) * 32 + u * 8;
    }
    csrc[k2] = v;
  }
  float vst[2][2][4], ist[2][2][4];
#pragma unroll
  for (int rp = 0; rp < 2; ++rp)
#pragma unroll
    for (int ch = 0; ch < 2; ++ch)
#pragma unroll
      for (int r = 0; r < 4; ++r) { vst[rp][ch][r] = 0.f; ist[rp][ch][r] = 0.f; }

  for (int t = 0; t < 16; ++t) {
    __syncthreads();
    {
      const unsigned short* zt = z1bf + (size_t)t * 1048576;
      uint4* imgu4 = (uint4*)&img[0][0][0];
#pragma unroll
      for (int k2 = 0; k2 < 7; ++k2) {
        int e = tid + k2 * 256;
        if (e < 1620) {
          uint4 val = {0, 0, 0, 0};
          if (csrc[k2] >= 0) val = *(const uint4*)(zt + csrc[k2]);
          imgu4[e] = val;
        }
      }
    }
    __syncthreads();
    f32x4 acc[2][2] = {};
#pragma unroll
    for (int s9 = 0; s9 < 9; ++s9) {
      const int dy = s9 / 3, dx = s9 % 3;
      bf16x8 a[2][2];
#pragma unroll
      for (int rp = 0; rp < 2; ++rp)
#pragma unroll
        for (int ch = 0; ch < 2; ++ch)
          a[rp][ch] = *(const bf16x8*)&img[4 * w + 2 * rp + ry + dy][ch * 8 + xi + dx][8 * lg];
#pragma unroll
      for (int sp = 0; sp < 3; ++sp)
#pragma unroll
        for (int rp = 0; rp < 2; ++rp)
#pragma unroll
          for (int ch = 0; ch < 2; ++ch)
            acc[rp][ch] = mfma16(a[rp][ch], bw[sp][s9], acc[rp][ch]);
    }
    // LIF + wave-local pre-pool store
#pragma unroll
    for (int rp = 0; rp < 2; ++rp)
#pragma unroll
      for (int ch = 0; ch < 2; ++ch)
#pragma unroll
        for (int r = 0; r < 4; ++r) {
          int m = 4 * lg + r;
          float z = lif1(acc[rp][ch][r], 0.2f, vst[rp][ch][r], ist[rp][ch][r]);
          zpl[w][2 * rp + (m >> 3)][ch * 8 + (m & 7)][ll] = f2bf(z);
        }
    // wave-local pool: lane -> oc = ll; prow = lg>>1, pcol = (lg&1)*4 + pp
#pragma unroll
    for (int pp = 0; pp < 4; ++pp) {
      int prow = lg >> 1, pcol = (lg & 1) * 4 + pp;
      float zs = bf2f(zpl[w][2*prow][2*pcol][ll])   + bf2f(zpl[w][2*prow][2*pcol+1][ll]) +
                 bf2f(zpl[w][2*prow+1][2*pcol][ll]) + bf2f(zpl[w][2*prow+1][2*pcol+1][ll]);
      z2bf[(size_t)t * 524288 + ((b * 8 + w * 2 + prow) * 8 + pcol) * 64 + ocg * 16 + ll]
          = f2bf(0.25f * zs);
    }
  }
}

// ---------- conv3 (64->128) MFMA full-K, B in REGS (54 frags) -> z3t[t] ----------
// grid 1024 = ocg(8: 16 oc) x b(128); 256 thr = 4 waves (row-pairs).
__global__ __launch_bounds__(256, 2) void k_conv3(const unsigned short* __restrict__ z2bf,
    const unsigned short* __restrict__ wpk, unsigned short* __restrict__ z3t)
{
  const int bid = blockIdx.x;
  const int ocg = bid & 7, b = bid >> 3;
  const int tid = threadIdx.x;
  __shared__ __align__(16) unsigned short img[10][12][72];
  __shared__ __align__(16) unsigned short zpl[4][16][18];
  const int w = tid >> 6, l = tid & 63;
  const int lg = l >> 4, ll = l & 15;
  const int ry = ll >> 3, xi = ll & 7;
  // B fragments in registers, loaded once (t-invariant): 54 frags = 216 VGPR
  bf16x8 bw[2][3][9];
  {
    const unsigned short* wp = wpk + ocg * 27648;
#pragma unroll
    for (int ics = 0; ics < 2; ++ics)
#pragma unroll
      for (int sp = 0; sp < 3; ++sp)
#pragma unroll
        for (int s9 = 0; s9 < 9; ++s9)
          bw[ics][sp][s9] = *(const bf16x8*)(wp + ics * 13824 +
                                             ((sp * 9 + s9) * 4 + lg) * 128 + ll * 8);
  }
  int csrc[5];
#pragma unroll
  for (int k2 = 0; k2 < 5; ++k2) {
    int e = tid + k2 * 256;
    int v = -1;
    if (e < 1080) {
      int s = e / 9, u = e % 9;
      int row = s / 12, col = s % 12;
      int gy = row - 1, gx = col - 1;
      if (u < 8 && gy >= 0 && gy < 8 && gx >= 0 && gx < 8)
        v = ((b * 8 + gy) * 8 + gx) * 64 + u * 8;
    }
    csrc[k2] = v;
  }
  float vst[4], ist[4];
#pragma unroll
  for (int r = 0; r < 4; ++r) { vst[r] = 0.f; ist[r] = 0.f; }

  for (int t = 0; t < 16; ++t) {
    __syncthreads();
    {
      const unsigned short* zt = z2bf + (size_t)t * 524288;
      uint4* imgu4 = (uint4*)&img[0][0][0];
#pragma unroll
      for (int k2 = 0; k2 < 5; ++k2) {
        int e = tid + k2 * 256;
        if (e < 1080) {
          uint4 val = {0, 0, 0, 0};
          if (csrc[k2] >= 0) val = *(const uint4*)(zt + csrc[k2]);
          imgu4[e] = val;
        }
      }
    }
    __syncthreads();
    f32x4 acc = {};
#pragma unroll
    for (int ics = 0; ics < 2; ++ics)
#pragma unroll
      for (int s9 = 0; s9 < 9; ++s9) {
        const int dy = s9 / 3, dx = s9 % 3;
        bf16x8 a = *(const bf16x8*)&img[2 * w + ry + dy][xi + dx][ics * 32 + 8 * lg];
#pragma unroll
        for (int sp = 0; sp < 3; ++sp)
          acc = mfma16(a, bw[ics][sp][s9], acc);
      }
    // LIF + wave-local pool
#pragma unroll
    for (int r = 0; r < 4; ++r) {
      int px = 4 * lg + r;
      float z = lif1(acc[r], 0.1f, vst[r], ist[r]);
      zpl[w][px][ll] = f2bf(z);
    }
    float zsum = bf2f(zpl[w][2*lg][ll])   + bf2f(zpl[w][2*lg+1][ll]) +
                 bf2f(zpl[w][8+2*lg][ll]) + bf2f(zpl[w][9+2*lg][ll]);
    z3t[(size_t)t * 262144 + b * 2048 + (ocg * 16 + ll) * 16 + w * 4 + lg]
        = f2bf(0.25f * zsum);
  }
}

// ---------- fc1 (2048->1024) MFMA, K-split 8, B in REGS (24 frags) ----------
// grid 1024 = kb8 x nb64(16 n) x bb2; 256 thr = 4 waves (bt). LDS = 32 KB slab only.
__global__ __launch_bounds__(256) void k_fc1(const unsigned short* __restrict__ z3t,
    const float* __restrict__ wf1, float* __restrict__ P1)
{
  const int bid = blockIdx.x;
  const int kb = bid & 7, nb = (bid >> 3) & 63, bb = bid >> 9;
  const int tid = threadIdx.x;
  __shared__ __align__(16) unsigned short slab[16384];  // wl3 staging first, then A-slab
  // stage 3-split weights into slab[0..12288) (coalesced global read, 1 read/weight)
  for (int i = tid; i < 4096; i += 256) {
    int n = i >> 8, k = i & 255;
    float wv = wf1[(size_t)(nb * 16 + n) * 2048 + kb * 256 + k];
    unsigned short hi = f2bf(wv);
    float r1 = wv - bf2f(hi);
    unsigned short mid = f2bf(r1);
    unsigned short lo = f2bf(r1 - bf2f(mid));
    int off = ((k >> 5) * 4 + ((k >> 3) & 3)) * 128 + n * 8 + (k & 7);
    slab[off] = hi; slab[4096 + off] = mid; slab[8192 + off] = lo;
  }
  __syncthreads();
  const int w = tid >> 6, l = tid & 63;
  const int lg = l >> 4, ll = l & 15;
  bf16x8 bwf[8][3];
#pragma unroll
  for (int ks = 0; ks < 8; ++ks)
#pragma unroll
    for (int sp = 0; sp < 3; ++sp)
      bwf[ks][sp] = *(const bf16x8*)&slab[sp * 4096 + (ks * 4 + lg) * 128 + ll * 8];
  const int arow = w * 16 + ll;
  const int bo = bb * 64 + w * 16;

  for (int t = 0; t < 16; ++t) {
    __syncthreads();                      // prior readers of slab done
    for (int gidx = tid; gidx < 2048; gidx += 256) {
      int row = gidx >> 5, gc = gidx & 31;
      const uint4* s = (const uint4*)(z3t + (size_t)t * 262144 +
                                      ((bb * 64 + row) * 2048 + kb * 256 + gc * 8));
      ((uint4*)slab)[row * 32 + (gc ^ (row & 7))] = *s;
    }
    __syncthreads();
    f32x4 acc = {};
#pragma unroll
    for (int ks = 0; ks < 8; ++ks) {
      bf16x8 a = *(const bf16x8*)&slab[(arow * 32 + ((ks * 4 + lg) ^ (arow & 7))) * 8];
#pragma unroll
      for (int sp = 0; sp < 3; ++sp)
        acc = mfma16(a, bwf[ks][sp], acc);
    }
    float* Pt = P1 + (size_t)t * 1048576 + (size_t)kb * 131072;
#pragma unroll
    for (int r = 0; r < 4; ++r)
      Pt[(bo + 4 * lg + r) * 1024 + nb * 16 + ll] = acc[r];
  }
}

// ---------- fc1 reduce + LIF(0.1), t-loop, state in regs -> z4bf[t][b][n] ----------
__global__ __launch_bounds__(256) void k_fc1b(const float* __restrict__ P1,
    unsigned short* __restrict__ z4bf)
{
  const int site = blockIdx.x * 256 + threadIdx.x;   // 131072 = b*1024+n
  float v = 0.f, ii = 0.f;
  for (int t = 0; t < 16; ++t) {
    const float* p = P1 + (size_t)t * 1048576 + site;
    float a = 0.f;
#pragma unroll
    for (int kb = 0; kb < 8; ++kb) a += p[(size_t)kb * 131072];
    float z = lif1(a, 0.1f, v, ii);
    z4bf[(size_t)t * 131072 + site] = f2bf(z);
  }
}

// ---------- out layer (1024->10) + LI + running max, t-loop, state in regs ----------
__global__ __launch_bounds__(256) void k_out(const unsigned short* __restrict__ z4bf,
    const float* __restrict__ wo, float* __restrict__ out)
{
  const int w = threadIdx.x >> 6, l = threadIdx.x & 63;
  const int b = blockIdx.x * 4 + w;
  float vo[10], io[10], om[10];
#pragma unroll
  for (int o = 0; o < 10; ++o) { vo[o] = 0.f; io[o] = 0.f; om[o] = 0.f; }
  for (int t = 0; t < 16; ++t) {
    float dot[10];
#pragma unroll
    for (int o = 0; o < 10; ++o) dot[o] = 0.f;
    for (int c = 0; c < 16; ++c) {
      const int n = c * 64 + l;
      float z = bf2f(z4bf[(size_t)t * 131072 + b * 1024 + n]);
#pragma unroll
      for (int o = 0; o < 10; ++o) dot[o] = fmaf(z, wo[o * 1024 + n], dot[o]);
    }
#pragma unroll
    for (int o = 0; o < 10; ++o)
#pragma unroll
      for (int d = 32; d > 0; d >>= 1) dot[o] += __shfl_down(dot[o], d);
    if (l == 0) {
#pragma unroll
      for (int o = 0; o < 10; ++o) {
        float vn = fmaf(0.1f, io[o] - vo[o], vo[o]);
        io[o] = fmaf(0.8f, io[o], dot[o]);
        vo[o] = vn;
        om[o] = (t == 0) ? vn : fmaxf(om[o], vn);
      }
    }
  }
  if (l == 0) {
#pragma unroll
    for (int o = 0; o < 10; ++o) out[b * 10 + o] = om[o];
  }
}

extern "C" void kernel_launch(void* const* d_in, const int* in_sizes, int n_in,
                              void* d_out, int out_size, void* d_ws, size_t ws_size,
                              hipStream_t stream)
{
  const float* x   = (const float*)d_in[0];   // (16,128,3,32,32)
  const float* wc1 = (const float*)d_in[1];   // (32,3,3,3)
  const float* wc2 = (const float*)d_in[2];   // (64,32,3,3)
  const float* wc3 = (const float*)d_in[3];   // (128,64,3,3)
  const float* wf1 = (const float*)d_in[4];   // (1024,2048)
  const float* wo  = (const float*)d_in[5];   // (10,1024)
  float* out = (float*)d_out;                 // (128,10)
  char* ws = (char*)d_ws;

  unsigned short* z1bf = (unsigned short*)(ws + 0);          // [16][128,16,16,32]
  unsigned short* z2bf = (unsigned short*)(ws + 33554432);   // [16][128,8,8,64]
  unsigned short* z3t  = (unsigned short*)(ws + 50331648);   // [16][128,2048]
  unsigned short* z4bf = (unsigned short*)(ws + 58720256);   // [16][128,1024]
  float* P1            = (float*)(ws + 62914560);            // [16][8][131072]
  unsigned short* wc2pk = (unsigned short*)(ws + 130023424);
  unsigned short* wc3pk = (unsigned short*)(ws + 130134016);

  k_pack2<<<216, 256, 0, stream>>>(wc2, wc2pk);
  k_pack3<<<1728, 256, 0, stream>>>(wc3, wc3pk);

  k_conv1<<<1024, 256, 0, stream>>>(x, wc1, z1bf);
  k_conv2<<<512, 256, 0, stream>>>(z1bf, wc2pk, z2bf);
  k_conv3<<<1024, 256, 0, stream>>>(z2bf, wc3pk, z3t);
  k_fc1 <<<1024, 256, 0, stream>>>(z3t, wf1, P1);
  k_fc1b<<<512, 256, 0, stream>>>(P1, z4bf);
  k_out <<<32, 256, 0, stream>>>(z4bf, wo, out);
}